// Round 4
// baseline (286.591 us; speedup 1.0000x reference)
//
#include <hip/hip_runtime.h>
#include <math.h>

namespace {
constexpr int B_ = 32, I_ = 2048, J_ = 64, D_ = 8, E_ = 16;
constexpr int WAVES = 16, THREADS = 1024;  // 16 waves: 8 batch-groups x 2 j-halves
constexpr int BPW = 4;                     // batches per wave
constexpr int WTILE = J_ * D_ * E_;        // 8192 floats = 32 KB per W[i]
constexpr int WQ = WTILE / 4;              // 2048 quads
constexpr int PART = B_ * J_ * E_;         // 32768 floats per i-chunk partial
constexpr int VSZ = B_ * J_ * E_;
}

// async global->LDS, 16B/lane. LDS dest linear; XOR-swizzle lives in the
// pre-permuted global source (both-sides rule): LDS[p] = Wtile[p ^ ((p>>5)&7)]
// (involution: XOR touches only bits 0-2, key bits 5-7 unchanged).
__device__ __forceinline__ void gload_lds16(const float* g, float* l) {
  __builtin_amdgcn_global_load_lds(
      (const __attribute__((address_space(1))) void*)g,
      (__attribute__((address_space(3))) void*)l, 16, 0, 0);
}

// One routing pass. Block = 16 waves = 8 batch-groups x 2 j-half-waves,
// covering ALL 32 batches -> W staged once per pass. Lane = (h, jl):
// h = e-half (8 e's), jl = j within half; wave w: group g = w>>1, jh = w&1.
// Per-lane state: uh/acc/vv [4][8] -> fits 4 waves/SIMD without spills.
template <int MODE, int NIT>
__global__ __launch_bounds__(THREADS, 4) void caps_pass(
    const float* __restrict__ x, const float* __restrict__ W,
    const float* __restrict__ v, float* __restrict__ partial) {
  __shared__ float Wlds[2][WTILE];   // 2 x 32 KiB
  __shared__ float sm[2][WAVES][4];  // softmax cross-wave exchange (parity dbuf)
  const int tid = threadIdx.x;
  const int w = tid >> 6, lane = tid & 63;
  const int jl = lane & 31, h = lane >> 5;
  const int g = w >> 1, jh = w & 1;
  const int j = jh * 32 + jl;
  const int b0 = g * BPW;
  const int i0 = (int)blockIdx.x * NIT;
  const int sw = jl & 7;

  float vv[BPW][8];
  if (MODE == 1) {
#pragma unroll
    for (int bb = 0; bb < BPW; ++bb) {
      const float4* vp = reinterpret_cast<const float4*>(
          v + ((size_t)(b0 + bb) * J_ + j) * E_ + h * 8);
      const float4 t0 = vp[0], t1 = vp[1];
      vv[bb][0] = t0.x; vv[bb][1] = t0.y; vv[bb][2] = t0.z; vv[bb][3] = t0.w;
      vv[bb][4] = t1.x; vv[bb][5] = t1.y; vv[bb][6] = t1.z; vv[bb][7] = t1.w;
    }
  }

  float acc[BPW][8];
#pragma unroll
  for (int bb = 0; bb < BPW; ++bb)
#pragma unroll
    for (int e = 0; e < 8; ++e) acc[bb][e] = 0.0f;

  // prologue: stage W[i0] (2048 quads = 16 waves x 2 instr x 64 lanes)
  {
    const float* Wt = W + (size_t)i0 * WTILE;
#pragma unroll
    for (int it = 0; it < 2; ++it) {
      const int p = (w * 2 + it) * 64 + lane;
      const int src = p ^ ((p >> 5) & 7);
      gload_lds16(Wt + (size_t)src * 4, &Wlds[0][p * 4]);
    }
  }
  __syncthreads();

#pragma unroll 1
  for (int t = 0; t < NIT; ++t) {
    const int cur = t & 1;
    if (t + 1 < NIT) {
      const float* Wt = W + (size_t)(i0 + t + 1) * WTILE;
#pragma unroll
      for (int it = 0; it < 2; ++it) {
        const int p = (w * 2 + it) * 64 + lane;
        const int src = p ^ ((p >> 5) & 7);
        gload_lds16(Wt + (size_t)src * 4, &Wlds[cur ^ 1][p * 4]);
      }
    }
    const int i = i0 + t;
    // x[b][i][0..7] -- wave-uniform (scalarizes to SGPR loads)
    float xs[BPW][D_];
#pragma unroll
    for (int bb = 0; bb < BPW; ++bb) {
      const float4* xp = reinterpret_cast<const float4*>(
          x + ((size_t)(b0 + bb) * I_ + i) * D_);
      const float4 t0 = xp[0], t1 = xp[1];
      xs[bb][0] = t0.x; xs[bb][1] = t0.y; xs[bb][2] = t0.z; xs[bb][3] = t0.w;
      xs[bb][4] = t1.x; xs[bb][5] = t1.y; xs[bb][6] = t1.z; xs[bb][7] = t1.w;
    }

    float uh[BPW][8];
#pragma unroll
    for (int bb = 0; bb < BPW; ++bb)
#pragma unroll
      for (int e = 0; e < 8; ++e) uh[bb][e] = 0.0f;

    const float* buf = Wlds[cur];
    const int qbase = jh * 1024 + jl * 32 + h * 2;  // quad idx: j*32 + d*4 + h*2 + c
#pragma unroll
    for (int d = 0; d < D_; ++d) {
#pragma unroll
      for (int c = 0; c < 2; ++c) {
        const int q = qbase + d * 4 + c;
        const float4 quad =
            *reinterpret_cast<const float4*>(buf + (size_t)(q ^ sw) * 4);
        const int e0 = c * 4;
#pragma unroll
        for (int bb = 0; bb < BPW; ++bb) {
          uh[bb][e0 + 0] = fmaf(xs[bb][d], quad.x, uh[bb][e0 + 0]);
          uh[bb][e0 + 1] = fmaf(xs[bb][d], quad.y, uh[bb][e0 + 1]);
          uh[bb][e0 + 2] = fmaf(xs[bb][d], quad.z, uh[bb][e0 + 2]);
          uh[bb][e0 + 3] = fmaf(xs[bb][d], quad.w, uh[bb][e0 + 3]);
        }
      }
    }

    if (MODE == 0) {
#pragma unroll
      for (int bb = 0; bb < BPW; ++bb)
#pragma unroll
        for (int e = 0; e < 8; ++e) acc[bb][e] += uh[bb][e];
      __syncthreads();  // all reads of buf[cur] done; next staging may overwrite
    } else {
      float pr[BPW], ssum[BPW];
#pragma unroll
      for (int bb = 0; bb < BPW; ++bb) {
        float l0 = 0.f, l1 = 0.f;
#pragma unroll
        for (int e = 0; e < 8; e += 2) {
          l0 = fmaf(uh[bb][e + 0], vv[bb][e + 0], l0);
          l1 = fmaf(uh[bb][e + 1], vv[bb][e + 1], l1);
        }
        float lg = l0 + l1;
        lg += __shfl_xor(lg, 32);  // combine e-halves -> full dot for this j
        // |lg| <= ~30 -> expf safe in fp32 without max-subtraction
        const float p = __expf(lg);
        float s = p;  // sum over this wave's 32 j's
        s += __shfl_xor(s, 1);
        s += __shfl_xor(s, 2);
        s += __shfl_xor(s, 4);
        s += __shfl_xor(s, 8);
        s += __shfl_xor(s, 16);
        pr[bb] = p;
        ssum[bb] = s;
      }
      if (lane == 0) {
        float4 t4;
        t4.x = ssum[0]; t4.y = ssum[1]; t4.z = ssum[2]; t4.w = ssum[3];
        *reinterpret_cast<float4*>(&sm[t & 1][w][0]) = t4;
      }
      __syncthreads();  // doubles as buf[cur] read-complete barrier
      const float4 o = *reinterpret_cast<const float4*>(&sm[t & 1][w ^ 1][0]);
      const float c0 = pr[0] / (ssum[0] + o.x);
      const float c1 = pr[1] / (ssum[1] + o.y);
      const float c2 = pr[2] / (ssum[2] + o.z);
      const float c3 = pr[3] / (ssum[3] + o.w);
#pragma unroll
      for (int e = 0; e < 8; ++e) {
        acc[0][e] = fmaf(c0, uh[0][e], acc[0][e]);
        acc[1][e] = fmaf(c1, uh[1][e], acc[1][e]);
        acc[2][e] = fmaf(c2, uh[2][e], acc[2][e]);
        acc[3][e] = fmaf(c3, uh[3][e], acc[3][e]);
      }
    }
  }

  // partial[chunk][b][j][e]; lane writes e = h*8 .. h*8+7 (two float4s)
  const float scale = (MODE == 0) ? (1.0f / 64.0f) : 1.0f;
  float* op = partial + (size_t)blockIdx.x * PART;
#pragma unroll
  for (int bb = 0; bb < BPW; ++bb) {
    float* dst = op + ((size_t)(b0 + bb) * J_ + j) * E_ + h * 8;
    float4 t0, t1;
    t0.x = acc[bb][0] * scale; t0.y = acc[bb][1] * scale;
    t0.z = acc[bb][2] * scale; t0.w = acc[bb][3] * scale;
    t1.x = acc[bb][4] * scale; t1.y = acc[bb][5] * scale;
    t1.z = acc[bb][6] * scale; t1.w = acc[bb][7] * scale;
    reinterpret_cast<float4*>(dst)[0] = t0;
    reinterpret_cast<float4*>(dst)[1] = t1;
  }
}

// Sum nic i-chunk partials for one (b, j-octet), squash, emit v.
// mode 0: v1 = squash(s); vsum = v1
// mode 1: vsum += squash(s)
// mode 2: out = squash(s)
__global__ __launch_bounds__(128) void caps_reduce(
    const float* __restrict__ partial, float* __restrict__ v1,
    float* __restrict__ vsum, float* __restrict__ out, const int mode,
    const int nic) {
  const int b = blockIdx.x >> 3;
  const int jg = blockIdx.x & 7;
  const int t = threadIdx.x;
  const int e = t & (E_ - 1);
  const int j = jg * 8 + (t >> 4);
  const float* p = partial + (size_t)b * (J_ * E_) + j * E_ + e;
  float s = 0.0f;
#pragma unroll 8
  for (int icb = 0; icb < nic; ++icb) s += p[(size_t)icb * PART];
  float sq = s * s;
  sq += __shfl_xor(sq, 1);
  sq += __shfl_xor(sq, 2);
  sq += __shfl_xor(sq, 4);
  sq += __shfl_xor(sq, 8);
  const float scale = sq / ((1.0f + sq) * sqrtf(sq));
  const float vv = s * scale;
  const int idx = (b * J_ + j) * E_ + e;
  if (mode == 0) {
    v1[idx] = vv;
    vsum[idx] = vv;
  } else if (mode == 1) {
    vsum[idx] += vv;
  } else {
    out[idx] = vv;
  }
}

extern "C" void kernel_launch(void* const* d_in, const int* in_sizes, int n_in,
                              void* d_out, int out_size, void* d_ws,
                              size_t ws_size, hipStream_t stream) {
  const float* x = (const float*)d_in[0];
  const float* W = (const float*)d_in[1];
  float* out = (float*)d_out;
  float* partial = (float*)d_ws;

  // NI=8 -> 256 chunks, partial = 32 MiB (ws >= 33.8 MiB verified in r3).
  const size_t need = ((size_t)256 * PART + 2 * VSZ) * sizeof(float);
  const bool big = ws_size >= need;
  const int nic = big ? 256 : 128;  // fallback NI=16 -> 128 chunks (16 MiB)
  float* v1 = partial + (size_t)nic * PART;
  float* vsum = v1 + VSZ;

  if (big) {
    caps_pass<0, 8><<<256, THREADS, 0, stream>>>(x, W, nullptr, partial);
    caps_reduce<<<B_ * 8, 128, 0, stream>>>(partial, v1, vsum, out, 0, nic);
    caps_pass<1, 8><<<256, THREADS, 0, stream>>>(x, W, v1, partial);
    caps_reduce<<<B_ * 8, 128, 0, stream>>>(partial, v1, vsum, out, 1, nic);
    caps_pass<1, 8><<<256, THREADS, 0, stream>>>(x, W, vsum, partial);
    caps_reduce<<<B_ * 8, 128, 0, stream>>>(partial, v1, vsum, out, 2, nic);
  } else {
    caps_pass<0, 16><<<128, THREADS, 0, stream>>>(x, W, nullptr, partial);
    caps_reduce<<<B_ * 8, 128, 0, stream>>>(partial, v1, vsum, out, 0, nic);
    caps_pass<1, 16><<<128, THREADS, 0, stream>>>(x, W, v1, partial);
    caps_reduce<<<B_ * 8, 128, 0, stream>>>(partial, v1, vsum, out, 1, nic);
    caps_pass<1, 16><<<128, THREADS, 0, stream>>>(x, W, vsum, partial);
    caps_reduce<<<B_ * 8, 128, 0, stream>>>(partial, v1, vsum, out, 2, nic);
  }
}

// Round 5
// 190.034 us; speedup vs baseline: 1.5081x; 1.5081x over previous
//
#include <hip/hip_runtime.h>
#include <math.h>

namespace {
constexpr int B_ = 32, I_ = 2048, J_ = 64, D_ = 8, E_ = 16;
constexpr int WAVES = 8, THREADS = 512;      // 4 batch-groups x 2 j/e-halves
constexpr int BPW = 4;                       // batches per wave (reg accum)
constexpr int BBLK = 16;                     // batches per block
constexpr int WTILE = J_ * D_ * E_;          // 8192 floats = 32 KB per W[i]
constexpr int PART_STRIDE = BBLK * J_ * E_;  // 16384 floats per block slot
constexpr int VSZ = B_ * J_ * E_;            // 32768
}

// async global->LDS, 16B/lane. LDS dest linear; XOR-swizzle lives in the
// pre-permuted global source (both-sides rule): LDS[p] = Wtile[p ^ ((p>>5)&7)]
// (involution: XOR touches only bits 0-2, key bits 5-7 unchanged).
__device__ __forceinline__ void gload_lds16(const float* g, float* l) {
  __builtin_amdgcn_global_load_lds(
      (const __attribute__((address_space(1))) void*)g,
      (__attribute__((address_space(3))) void*)l, 16, 0, 0);
}

// pin a wave-uniform float to an SGPR (x addresses are lane-independent)
__device__ __forceinline__ float rfl(float f) {
  return __builtin_bit_cast(
      float, __builtin_amdgcn_readfirstlane(__builtin_bit_cast(int, f)));
}

// One routing pass. Block = 8 waves = 4 batch-groups x 2 j-half-waves,
// 16 batches/block (2 batch-halves -> W staged twice per pass). Lane =
// (h, jl): h = e-half, jl = j-within-half; wave w: g = w>>1, jh = w&1.
// VGPR state: uh/acc/vv[4][8] = 96; x pinned to SGPRs via readfirstlane.
template <int MODE, int NIT>
__global__ __launch_bounds__(THREADS, 2) void caps_pass(
    const float* __restrict__ x, const float* __restrict__ W,
    const float* __restrict__ v, float* __restrict__ partial) {
  __shared__ float Wlds[2][WTILE];   // 2 x 32 KiB
  __shared__ float sm[2][WAVES][4];  // cross-half softmax sums (parity dbuf)
  const int tid = threadIdx.x;
  const int w = tid >> 6, lane = tid & 63;
  const int jl = lane & 31, h = lane >> 5;
  const int g = w >> 1, jh = w & 1;
  const int j = jh * 32 + jl;
  const int ic = (int)blockIdx.x >> 1;
  const int bh = (int)blockIdx.x & 1;
  const int b0 = bh * BBLK + g * BPW;
  const int i0 = ic * NIT;
  const int sw = jl & 7;

  float vv[BPW][8];
  if (MODE == 1) {
#pragma unroll
    for (int bb = 0; bb < BPW; ++bb) {
      const float4* vp = reinterpret_cast<const float4*>(
          v + ((size_t)(b0 + bb) * J_ + j) * E_ + h * 8);
      const float4 t0 = vp[0], t1 = vp[1];
      vv[bb][0] = t0.x; vv[bb][1] = t0.y; vv[bb][2] = t0.z; vv[bb][3] = t0.w;
      vv[bb][4] = t1.x; vv[bb][5] = t1.y; vv[bb][6] = t1.z; vv[bb][7] = t1.w;
    }
  }

  float acc[BPW][8];
#pragma unroll
  for (int bb = 0; bb < BPW; ++bb)
#pragma unroll
    for (int e = 0; e < 8; ++e) acc[bb][e] = 0.0f;

  // prologue: stage W[i0] (2048 quads = 8 waves x 4 instr x 64 lanes)
  {
    const float* Wt = W + (size_t)i0 * WTILE;
#pragma unroll
    for (int it = 0; it < 4; ++it) {
      const int p = (w * 4 + it) * 64 + lane;
      const int src = p ^ ((p >> 5) & 7);
      gload_lds16(Wt + (size_t)src * 4, &Wlds[0][p * 4]);
    }
  }
  __syncthreads();

#pragma unroll 1
  for (int t = 0; t < NIT; ++t) {
    const int cur = t & 1;
    if (t + 1 < NIT) {
      const float* Wt = W + (size_t)(i0 + t + 1) * WTILE;
#pragma unroll
      for (int it = 0; it < 4; ++it) {
        const int p = (w * 4 + it) * 64 + lane;
        const int src = p ^ ((p >> 5) & 7);
        gload_lds16(Wt + (size_t)src * 4, &Wlds[cur ^ 1][p * 4]);
      }
    }
    const int i = i0 + t;
    // x[b][i][0..7]: wave-uniform -> pin to SGPRs (frees 32 VGPRs)
    float xs[BPW][D_];
#pragma unroll
    for (int bb = 0; bb < BPW; ++bb) {
      const float4* xp = reinterpret_cast<const float4*>(
          x + ((size_t)(b0 + bb) * I_ + i) * D_);
      const float4 t0 = xp[0], t1 = xp[1];
      xs[bb][0] = rfl(t0.x); xs[bb][1] = rfl(t0.y);
      xs[bb][2] = rfl(t0.z); xs[bb][3] = rfl(t0.w);
      xs[bb][4] = rfl(t1.x); xs[bb][5] = rfl(t1.y);
      xs[bb][6] = rfl(t1.z); xs[bb][7] = rfl(t1.w);
    }

    const float* buf = Wlds[cur];
    const int qbase = jh * 1024 + jl * 32 + h * 2;  // quad: j*32 + d*4 + h*2 + c

    if (MODE == 0) {
      // c uniform: accumulate x.W directly, scale 1/64 at the end
#pragma unroll
      for (int d = 0; d < D_; ++d) {
#pragma unroll
        for (int c = 0; c < 2; ++c) {
          const int q = qbase + d * 4 + c;
          const float4 quad =
              *reinterpret_cast<const float4*>(buf + (size_t)(q ^ sw) * 4);
          const int e0 = c * 4;
#pragma unroll
          for (int bb = 0; bb < BPW; ++bb) {
            acc[bb][e0 + 0] = fmaf(xs[bb][d], quad.x, acc[bb][e0 + 0]);
            acc[bb][e0 + 1] = fmaf(xs[bb][d], quad.y, acc[bb][e0 + 1]);
            acc[bb][e0 + 2] = fmaf(xs[bb][d], quad.z, acc[bb][e0 + 2]);
            acc[bb][e0 + 3] = fmaf(xs[bb][d], quad.w, acc[bb][e0 + 3]);
          }
        }
      }
      __syncthreads();  // all reads of buf[cur] done before next overwrite
    } else {
      float uh[BPW][8];
#pragma unroll
      for (int bb = 0; bb < BPW; ++bb)
#pragma unroll
        for (int e = 0; e < 8; ++e) uh[bb][e] = 0.0f;
#pragma unroll
      for (int d = 0; d < D_; ++d) {
#pragma unroll
        for (int c = 0; c < 2; ++c) {
          const int q = qbase + d * 4 + c;
          const float4 quad =
              *reinterpret_cast<const float4*>(buf + (size_t)(q ^ sw) * 4);
          const int e0 = c * 4;
#pragma unroll
          for (int bb = 0; bb < BPW; ++bb) {
            uh[bb][e0 + 0] = fmaf(xs[bb][d], quad.x, uh[bb][e0 + 0]);
            uh[bb][e0 + 1] = fmaf(xs[bb][d], quad.y, uh[bb][e0 + 1]);
            uh[bb][e0 + 2] = fmaf(xs[bb][d], quad.z, uh[bb][e0 + 2]);
            uh[bb][e0 + 3] = fmaf(xs[bb][d], quad.w, uh[bb][e0 + 3]);
          }
        }
      }
      float pr[BPW], ssum[BPW];
#pragma unroll
      for (int bb = 0; bb < BPW; ++bb) {
        float l0 = 0.f, l1 = 0.f;
#pragma unroll
        for (int e = 0; e < 8; e += 2) {
          l0 = fmaf(uh[bb][e + 0], vv[bb][e + 0], l0);
          l1 = fmaf(uh[bb][e + 1], vv[bb][e + 1], l1);
        }
        float lg = l0 + l1;
        lg += __shfl_xor(lg, 32);  // join e-halves -> full dot for this j
        const float p = __expf(lg);  // |lg| small; fp32 exp safe w/o max-sub
        float s = p;  // sum over this wave's 32 j's
        s += __shfl_xor(s, 1);
        s += __shfl_xor(s, 2);
        s += __shfl_xor(s, 4);
        s += __shfl_xor(s, 8);
        s += __shfl_xor(s, 16);
        pr[bb] = p;
        ssum[bb] = s;
      }
      if (lane == 0) {
        float4 t4;
        t4.x = ssum[0]; t4.y = ssum[1]; t4.z = ssum[2]; t4.w = ssum[3];
        *reinterpret_cast<float4*>(&sm[t & 1][w][0]) = t4;
      }
      __syncthreads();  // also: buf[cur] reads complete, staging may proceed
      const float4 o = *reinterpret_cast<const float4*>(&sm[t & 1][w ^ 1][0]);
      const float c0 = pr[0] / (ssum[0] + o.x);
      const float c1 = pr[1] / (ssum[1] + o.y);
      const float c2 = pr[2] / (ssum[2] + o.z);
      const float c3 = pr[3] / (ssum[3] + o.w);
#pragma unroll
      for (int e = 0; e < 8; ++e) {
        acc[0][e] = fmaf(c0, uh[0][e], acc[0][e]);
        acc[1][e] = fmaf(c1, uh[1][e], acc[1][e]);
        acc[2][e] = fmaf(c2, uh[2][e], acc[2][e]);
        acc[3][e] = fmaf(c3, uh[3][e], acc[3][e]);
      }
    }
  }

  // partial[block][blocal][j][e]; lane writes e = h*8 .. h*8+7
  const float scale = (MODE == 0) ? (1.0f / 64.0f) : 1.0f;
  float* op = partial + (size_t)blockIdx.x * PART_STRIDE;
#pragma unroll
  for (int bb = 0; bb < BPW; ++bb) {
    float* dst = op + ((size_t)(g * BPW + bb) * J_ + j) * E_ + h * 8;
    float4 t0, t1;
    t0.x = acc[bb][0] * scale; t0.y = acc[bb][1] * scale;
    t0.z = acc[bb][2] * scale; t0.w = acc[bb][3] * scale;
    t1.x = acc[bb][4] * scale; t1.y = acc[bb][5] * scale;
    t1.z = acc[bb][6] * scale; t1.w = acc[bb][7] * scale;
    reinterpret_cast<float4*>(dst)[0] = t0;
    reinterpret_cast<float4*>(dst)[1] = t1;
  }
}

// Sum nic i-chunk partials for one (b, j-octet), squash, emit v.
// mode 0: v1 = squash(s); vsum = v1
// mode 1: vsum += squash(s)
// mode 2: out = squash(s)
__global__ __launch_bounds__(128) void caps_reduce(
    const float* __restrict__ partial, float* __restrict__ v1,
    float* __restrict__ vsum, float* __restrict__ out, const int mode,
    const int nic) {
  const int b = blockIdx.x >> 3;
  const int jg = blockIdx.x & 7;
  const int t = threadIdx.x;
  const int e = t & (E_ - 1);
  const int j = jg * 8 + (t >> 4);
  const int bh = b >> 4;
  const int bb = b & (BBLK - 1);
  const float* p =
      partial + (size_t)bh * PART_STRIDE + (size_t)bb * (J_ * E_) + j * E_ + e;
  float s = 0.0f;
#pragma unroll 8
  for (int icb = 0; icb < nic; ++icb)
    s += p[(size_t)icb * (2 * PART_STRIDE)];
  float sq = s * s;
  sq += __shfl_xor(sq, 1);
  sq += __shfl_xor(sq, 2);
  sq += __shfl_xor(sq, 4);
  sq += __shfl_xor(sq, 8);
  const float scale = sq / ((1.0f + sq) * sqrtf(sq));
  const float vv = s * scale;
  const int idx = (b * J_ + j) * E_ + e;
  if (mode == 0) {
    v1[idx] = vv;
    vsum[idx] = vv;
  } else if (mode == 1) {
    vsum[idx] += vv;
  } else {
    out[idx] = vv;
  }
}

extern "C" void kernel_launch(void* const* d_in, const int* in_sizes, int n_in,
                              void* d_out, int out_size, void* d_ws,
                              size_t ws_size, hipStream_t stream) {
  const float* x = (const float*)d_in[0];
  const float* W = (const float*)d_in[1];
  float* out = (float*)d_out;
  float* partial = (float*)d_ws;

  // NI=8 -> grid 512 (2 blocks/CU), partial = 32 MiB (big path verified r3).
  const size_t need = ((size_t)512 * PART_STRIDE + 2 * VSZ) * sizeof(float);
  const bool big = ws_size >= need;
  const int nblk = big ? 512 : 256;
  const int nic = big ? 256 : 128;
  float* v1 = partial + (size_t)nblk * PART_STRIDE;
  float* vsum = v1 + VSZ;

  if (big) {
    caps_pass<0, 8><<<nblk, THREADS, 0, stream>>>(x, W, nullptr, partial);
    caps_reduce<<<B_ * 8, 128, 0, stream>>>(partial, v1, vsum, out, 0, nic);
    caps_pass<1, 8><<<nblk, THREADS, 0, stream>>>(x, W, v1, partial);
    caps_reduce<<<B_ * 8, 128, 0, stream>>>(partial, v1, vsum, out, 1, nic);
    caps_pass<1, 8><<<nblk, THREADS, 0, stream>>>(x, W, vsum, partial);
    caps_reduce<<<B_ * 8, 128, 0, stream>>>(partial, v1, vsum, out, 2, nic);
  } else {
    caps_pass<0, 16><<<nblk, THREADS, 0, stream>>>(x, W, nullptr, partial);
    caps_reduce<<<B_ * 8, 128, 0, stream>>>(partial, v1, vsum, out, 0, nic);
    caps_pass<1, 16><<<nblk, THREADS, 0, stream>>>(x, W, v1, partial);
    caps_reduce<<<B_ * 8, 128, 0, stream>>>(partial, v1, vsum, out, 1, nic);
    caps_pass<1, 16><<<nblk, THREADS, 0, stream>>>(x, W, vsum, partial);
    caps_reduce<<<B_ * 8, 128, 0, stream>>>(partial, v1, vsum, out, 2, nic);
  }
}